// Round 1
// 185.540 us; speedup vs baseline: 1.0734x; 1.0734x over previous
//
#include <hip/hip_runtime.h>
#include <hip/hip_bf16.h>

// GCN: x=emb[ids]; x1=relu(GCNConv(x,W1,b1)); y=Ahat@x1; out[g]=b2+(mean_g y)@W2
//
// R17: single-pass partition. The R16 5-kernel counting sort (p1/scanG/scanT/
// part/cnt2) is replaced by:
//  - k_ninfo: nodeInfo[n] = {bucket(9)|dstLocalGraph(12)} via batch[n] (no
//    binary search; bkBound redefined ceil-split so bucket = 8*o/L exactly).
//  - k_partA: ONE pass over edges. Per 2048-edge chunk: LDS histogram ->
//    pair-scan -> per-bucket global atomicAdd reservation into fixed-capacity
//    bucket slots (BKCAP=4096 >= 9-sigma of max bucket ~3450) -> LDS sort ->
//    coalesced run write-out. Intra-bucket order is nondeterministic; all
//    downstream sums are atomic/fp8-quantized already, so order is free.
//  - conv2+pool slices per (bucket, quarter) instead of per (graph, slice),
//    since graphs' edges are no longer contiguous across buckets.
// Keepers: fp8 e4m3 z rows, dense conv1 bins CL[node][type], dinvA table,
// branchless sentinel, int4 edge loads, XCD-aware conv2 mapping.

#define DDIM 128
#define GMAX 64
#define BPG  8                 // buckets per graph
#define NBK  (GMAX * BPG)      // 512 buckets
#define BKCAP 4096             // fixed slot capacity per bucket (pow2)
#define CHUNK 2048             // edges per partition block
#define MAXGN 2048             // max nodes per graph (mean 1563, +12 sigma)
typedef unsigned int uint;
typedef unsigned short ushort;
typedef float v2f __attribute__((ext_vector_type(2)));

// Setup: block 0 -> gBound[65] + bkBound[513]; blocks 1..17 -> t1 = emb@W1 rows.
__global__ void __launch_bounds__(256) k_setup(
        const int* __restrict__ batch, int N,
        int* __restrict__ gBound, int* __restrict__ bkBound,
        const float* __restrict__ emb, const float* __restrict__ W1,
        float* __restrict__ t1) {
    int t = threadIdx.x, b = blockIdx.x;
    if (b == 0) {
        __shared__ int gB[GMAX + 1];
        if (t <= GMAX) {
            int key = t, lo = 0, hi = N;
            while (lo < hi) {
                int mid = (lo + hi) >> 1;
                if (batch[mid] < key) lo = mid + 1; else hi = mid;
            }
            gB[t] = lo;
            gBound[t] = lo;
        }
        __syncthreads();
        for (int bk = t; bk <= NBK; bk += 256) {
            int v;
            if (bk == NBK) v = gB[GMAX];
            else {
                int g = bk >> 3, s = bk & 7;
                int A = gB[g], L = gB[g + 1] - A;
                // ceil-split so membership is exactly s = (8*o)/L; s=0 -> A.
                v = A + (int)(((long long)L * s + 7) / 8);
            }
            bkBound[bk] = v;
        }
    } else {
        int row = b - 1;                 // 0..16
        if (t < DDIM) {
            float acc = 0.f;
            for (int k = 0; k < DDIM; k++) acc += emb[row * DDIM + k] * W1[k * DDIM + t];
            t1[row * DDIM + t] = acc;
        }
    }
}

// nodeInfo[n] = {bucket(9) | dstLocalGraph(12)} ; graph id = batch[n].
__global__ void __launch_bounds__(256) k_ninfo(
        const int* __restrict__ batch, const int* __restrict__ gBound,
        uint* __restrict__ nodeInfo, int N) {
    int n = blockIdx.x * 256 + threadIdx.x;
    if (n >= N) return;
    int g = batch[n];
    int A = gBound[g], L = gBound[g + 1] - A;
    int o = n - A;                       // dLG, < 2048
    int s = (8 * o) / L;                 // exact bucket-in-graph (ceil-split)
    nodeInfo[n] = ((uint)(g * BPG + s) << 12) | (uint)o;
}

// Single-pass partition: per 2048-edge chunk, LDS sort by bucket + global
// atomic reservation into fixed-stride bucket slots.
__global__ void __launch_bounds__(256) k_partA(
        const int* __restrict__ src, const int* __restrict__ dst,
        const uint* __restrict__ nodeInfo, int* __restrict__ bkCnt,
        uint* __restrict__ partsKey, int E) {
    __shared__ int rk[NBK];
    __shared__ int runOff[NBK];
    __shared__ int base[NBK];
    __shared__ int sms[256];
    __shared__ uint sbuf[CHUNK];
    __shared__ ushort sb2[CHUNK];
    int t = threadIdx.x, b = blockIdx.x;
    int lo = b * CHUNK;
    int hi = lo + CHUNK; if (hi > E) hi = E;
    int cnt = hi - lo;
    for (int k = t; k < NBK; k += 256) rk[k] = 0;
    __syncthreads();
    uint key_[8]; int bk_[8], r_[8]; bool v_[8];
    if (cnt == CHUNK) {                       // full chunk: int4 loads
        int4 sA = *(const int4*)(src + lo + t * 4);
        int4 sB = *(const int4*)(src + lo + 1024 + t * 4);
        int4 dA = *(const int4*)(dst + lo + t * 4);
        int4 dB = *(const int4*)(dst + lo + 1024 + t * 4);
        int ss[8] = {sA.x, sA.y, sA.z, sA.w, sB.x, sB.y, sB.z, sB.w};
        int dd[8] = {dA.x, dA.y, dA.z, dA.w, dB.x, dB.y, dB.z, dB.w};
#pragma unroll
        for (int q = 0; q < 8; q++) {
            v_[q] = true;
            uint info = nodeInfo[dd[q]];      // random 4B gather, L2-resident
            bk_[q] = (int)(info >> 12);
            key_[q] = ((info & 0xFFFu) << 17) | (uint)ss[q];
        }
    } else {
#pragma unroll
        for (int q = 0; q < 8; q++) {
            int item = lo + q * 256 + t;
            v_[q] = item < hi;
            key_[q] = 0; bk_[q] = 0;
            if (v_[q]) {
                uint info = nodeInfo[dst[item]];
                bk_[q] = (int)(info >> 12);
                key_[q] = ((info & 0xFFFu) << 17) | (uint)src[item];
            }
        }
    }
#pragma unroll
    for (int q = 0; q < 8; q++)
        if (v_[q]) r_[q] = atomicAdd(&rk[bk_[q]], 1);
    __syncthreads();
    {   // pair-scan rk[512] -> runOff (exclusive)
        int v0 = rk[2 * t], v1 = rk[2 * t + 1];
        int run = v0 + v1;
        sms[t] = run; __syncthreads();
        for (int off = 1; off < 256; off <<= 1) {
            int a = (t >= off) ? sms[t - off] : 0;
            __syncthreads();
            sms[t] += a; __syncthreads();
        }
        int excl = sms[t] - run;
        runOff[2 * t] = excl;
        runOff[2 * t + 1] = excl + v0;
    }
    __syncthreads();
    // reserve global slots first (atomics in flight during LDS scatter)
    for (int k = t; k < NBK; k += 256) {
        int c = rk[k];
        if (c > 0) base[k] = k * BKCAP + atomicAdd(&bkCnt[k], c);
    }
#pragma unroll
    for (int q = 0; q < 8; q++)               // LDS sort by bucket
        if (v_[q]) {
            int p = runOff[bk_[q]] + r_[q];
            sbuf[p] = key_[q];
            sb2[p] = (ushort)bk_[q];
        }
    __syncthreads();
#pragma unroll
    for (int q = 0; q < 8; q++) {             // coalesced run write-out
        int p = q * 256 + t;
        if (p < cnt) {
            int bk = sb2[p];
            partsKey[base[bk] + (p - runOff[bk])] = sbuf[p];
        }
    }
}

// Per-bucket: count bucket-local dst -> nd (+ dense dinvA).
__global__ void __launch_bounds__(256) k_cnt2(
        const uint* __restrict__ partsKey, const int* __restrict__ bkBound,
        const int* __restrict__ bkCnt, const int* __restrict__ ids,
        float2* __restrict__ nd, float* __restrict__ dinvA) {
    __shared__ int cnt[256];
    int b = blockIdx.x, t = threadIdx.x;
    cnt[t] = 0;
    __syncthreads();
    int nodeLo = bkBound[b];
    int gOff = nodeLo - bkBound[(b >> 3) << 3];  // bucket offset within graph
    int lo = b * BKCAP, hi = lo + bkCnt[b];
    for (int idx = lo + t; idx < hi; idx += 256) {
        uint key = partsKey[idx];
        int dL = (int)((key >> 17) & 0xFFF) - gOff;
        atomicAdd(&cnt[dL], 1);
    }
    __syncthreads();
    int nn = bkBound[b + 1] - nodeLo;
    if (t < nn) {
        int i = nodeLo + t;
        float dinv = rsqrtf((float)(cnt[t] + 1));
        nd[i] = make_float2(dinv, __int_as_float(ids[i]));
        dinvA[i] = dinv;
    }
}

// Per-bucket conv1: LDS bins CL[node][type] (8-wide batched gathers), dense
// x1; z = dinv*x1 in FP8 e4m3 row-major; self-loop pool (fp32) -> poolY.
__global__ void __launch_bounds__(256) k_x1b(
        const uint* __restrict__ partsKey, const int* __restrict__ bkBound,
        const int* __restrict__ bkCnt, const float2* __restrict__ nd,
        const float* __restrict__ t1, const float* __restrict__ b1,
        ushort* __restrict__ z, float* __restrict__ poolY) {
    __shared__ float t1s[17 * DDIM];    // 8.7 KB
    __shared__ float CL[256 * 17];      // 17.4 KB
    __shared__ float2 ndL[256];
    __shared__ float bL[DDIM];
    __shared__ float redS[4][DDIM];     // self-pool reduce
    int b = blockIdx.x, t = threadIdx.x;
    int nodeLo = bkBound[b], nn = bkBound[b + 1] - nodeLo;
    int gOff = nodeLo - bkBound[(b >> 3) << 3];
    for (int k = t; k < 17 * DDIM; k += 256) t1s[k] = t1[k];
    for (int k = t; k < 256 * 17; k += 256) CL[k] = 0.f;
    if (t < DDIM) bL[t] = b1[t];
    if (t < nn) ndL[t] = nd[nodeLo + t];
    __syncthreads();
    int lo = b * BKCAP, hi = lo + bkCnt[b];
    for (int cb = lo; cb < hi; cb += 2048) {
        uint key_[8]; bool v_[8];
#pragma unroll
        for (int q = 0; q < 8; q++) {
            int idx = cb + q * 256 + t;
            v_[q] = idx < hi;
            key_[q] = v_[q] ? partsKey[idx] : 0u;
        }
#pragma unroll
        for (int q = 0; q < 8; q++) {
            if (v_[q]) {
                uint key = key_[q];
                int s = key & 0x1FFFF;
                int dL = (int)((key >> 17) & 0xFFF) - gOff;
                float2 ns = nd[s];              // random 8B gather (8 in flight)
                atomicAdd(&CL[dL * 17 + __float_as_int(ns.y)], ns.x);
            }
        }
    }
    __syncthreads();
    int lane = t & 63, wave = t >> 6;
    float sx = 0.f, sy = 0.f;                   // self-loop pool partials
    for (int n = wave; n < nn; n += 4) {
        float dinv = ndL[n].x;
        int ti = __float_as_int(ndL[n].y);
        float ax = dinv * t1s[ti * DDIM + lane];
        float ay = dinv * t1s[ti * DDIM + 64 + lane];
#pragma unroll
        for (int tt = 0; tt < 17; tt++) {
            float c = CL[n * 17 + tt];
            ax += c * t1s[tt * DDIM + lane];
            ay += c * t1s[tt * DDIM + 64 + lane];
        }
        float vx = bL[lane]      + dinv * ax;
        float vy = bL[64 + lane] + dinv * ay;
        vx = vx > 0.f ? vx : 0.f;
        vy = vy > 0.f ? vy : 0.f;
        // z = dinv * x1, fp8 e4m3 packed pair, row-major store
        int pk = __builtin_amdgcn_cvt_pk_fp8_f32(dinv * vx, dinv * vy, 0, false);
        z[(size_t)(nodeLo + n) * 64 + lane] = (ushort)(pk & 0xFFFF);
        float d2 = dinv * dinv;
        sx += d2 * vx;                           // self loop, fp32 path
        sy += d2 * vy;
    }
    redS[wave][lane] = sx;
    redS[wave][64 + lane] = sy;
    __syncthreads();
    if (wave == 0) {
        int g = b >> 3;
        float vx = redS[0][lane] + redS[1][lane] + redS[2][lane] + redS[3][lane];
        float vy = redS[0][64 + lane] + redS[1][64 + lane]
                 + redS[2][64 + lane] + redS[3][64 + lane];
        atomicAdd(&poolY[g * DDIM + lane], vx);
        atomicAdd(&poolY[g * DDIM + 64 + lane], vy);
    }
}

// conv2+pool: block owns one (bucket, quarter). Weight = dinv_d from LDS
// table; rows fp8 z (128 B). Branchless: sentinel dLG=2047, dinvG[2047]=0.
// XCD mapping: blocks on XCD x=(b&7) touch graphs x*8..x*8+7 only.
__global__ void __launch_bounds__(256) k_conv2g(
        const uint* __restrict__ partsKey, const int* __restrict__ bkCnt,
        const int* __restrict__ gBound, const float* __restrict__ dinvA,
        const ushort* __restrict__ z, float* __restrict__ poolY) {
    __shared__ float dinvG[MAXGN];      // 8 KB
    __shared__ uint  mk[4][64];
    __shared__ float red[4][DDIM];
    int t = threadIdx.x, lane = t & 63, wave = t >> 6;
    int b = blockIdx.x;
    int j = b >> 3;
    int g = (b & 7) * 8 + (j >> 5);
    int r = j & 31;
    int bk = g * BPG + (r >> 2);        // bucket-in-graph
    int q = r & 3;                      // quarter of bucket
    int nLo = gBound[g], nn = gBound[g + 1] - nLo;
    for (int k = t; k < nn; k += 256) dinvG[k] = dinvA[nLo + k];
    if (t == 0) dinvG[MAXGN - 1] = 0.f;          // sentinel weight
    __syncthreads();
    int c = bkCnt[bk];
    int base0 = bk * BKCAP;
    int s0 = base0 + (c * q) / 4;
    int s1 = base0 + (c * (q + 1)) / 4;
    const uint SENT = (uint)(MAXGN - 1) << 17;   // dLG=2047, src=0
    float ax = 0.f, ay = 0.f;
    for (int cb = s0 + wave * 64; cb < s1; cb += 4 * 64) {
        int idx = cb + lane;
        mk[wave][lane] = (idx < s1) ? partsKey[idx] : SENT;
#pragma unroll
        for (int jj = 0; jj < 64; jj += 16) {
            uint kk[16]; uint vv[16];
#pragma unroll
            for (int k = 0; k < 16; k++) kk[k] = mk[wave][jj + k];
#pragma unroll
            for (int k = 0; k < 16; k++)
                vv[k] = (uint)z[(size_t)(kk[k] & 0x1FFFF) * 64 + lane];
#pragma unroll
            for (int k = 0; k < 16; k++) {
                float w = dinvG[(kk[k] >> 17) & 0xFFF];  // LDS broadcast
                v2f f = __builtin_amdgcn_cvt_pk_f32_fp8((int)vv[k], false);
                ax += w * f.x;
                ay += w * f.y;
            }
        }
    }
    red[wave][lane] = ax;
    red[wave][64 + lane] = ay;
    __syncthreads();
    if (wave == 0) {
        float vx = red[0][lane] + red[1][lane] + red[2][lane] + red[3][lane];
        float vy = red[0][64 + lane] + red[1][64 + lane] + red[2][64 + lane] + red[3][64 + lane];
        atomicAdd(&poolY[g * DDIM + lane], vx);
        atomicAdd(&poolY[g * DDIM + 64 + lane], vy);
    }
}

// out[g] = b2 + (poolY[g]/cnt[g]) @ W2 ; cnt from gBound
__global__ void __launch_bounds__(128) k_out(
        const float* __restrict__ poolY, const int* __restrict__ gBound,
        const float* __restrict__ W2, const float* __restrict__ b2,
        float* __restrict__ out) {
    __shared__ float py[DDIM];
    int g = blockIdx.x, f = threadIdx.x;
    py[f] = poolY[g * DDIM + f];
    __syncthreads();
    float acc = 0.f;
    for (int k = 0; k < DDIM; k++) acc += py[k] * W2[k * DDIM + f];
    int c = gBound[g + 1] - gBound[g];
    out[g * DDIM + f] = (c > 0) ? (b2[f] + acc / (float)c) : 0.f;
}

extern "C" void kernel_launch(void* const* d_in, const int* in_sizes, int n_in,
                              void* d_out, int out_size, void* d_ws, size_t ws_size,
                              hipStream_t stream) {
    const int* node_ids = (const int*)d_in[0];
    const int* edge_index = (const int*)d_in[1];
    const int* batch = (const int*)d_in[2];
    const float* emb = (const float*)d_in[4];
    const float* W1 = (const float*)d_in[5];
    const float* b1 = (const float*)d_in[6];
    const float* W2 = (const float*)d_in[7];
    const float* b2 = (const float*)d_in[8];
    float* out = (float*)d_out;

    const int N = in_sizes[0];
    const int E = in_sizes[1] / 2;
    const int* src = edge_index;
    const int* dst = edge_index + E;

    char* ws = (char*)d_ws;
    size_t off = 0;
    auto carve = [&](size_t bytes) { char* p = ws + off; off = (off + bytes + 255) & ~size_t(255); return p; };
    ushort* z        = (ushort*)carve((size_t)N * 64 * 2);       // fp8x2, 128 B/row
    uint*   partsKey = (uint*)carve((size_t)NBK * BKCAP * 4);    // 8 MB, gapped
    float2* nd       = (float2*)carve((size_t)N * 8);
    float*  dinvA    = (float*)carve((size_t)N * 4);
    uint*   nodeInfo = (uint*)carve((size_t)N * 4);
    int*    gBound   = (int*)carve((GMAX + 1) * 4);
    int*    bkBound  = (int*)carve((NBK + 1) * 4);
    float*  t1       = (float*)carve(17 * DDIM * 4);
    float*  poolY    = (float*)carve((size_t)GMAX * DDIM * 4);   // 32 KB (256-aligned)
    int*    bkCnt    = (int*)carve(NBK * 4);                     // adjacent to poolY

    // single memset covers poolY (32 KB) + bkCnt (2 KB), carved contiguously
    hipMemsetAsync(poolY, 0, (size_t)GMAX * DDIM * 4 + NBK * 4, stream);

    int nblkE = (E + CHUNK - 1) / CHUNK;     // 782
    int nblkN = (N + 255) / 256;

    k_setup<<<18, 256, 0, stream>>>(batch, N, gBound, bkBound, emb, W1, t1);
    k_ninfo<<<nblkN, 256, 0, stream>>>(batch, gBound, nodeInfo, N);
    k_partA<<<nblkE, 256, 0, stream>>>(src, dst, nodeInfo, bkCnt, partsKey, E);
    k_cnt2<<<NBK, 256, 0, stream>>>(partsKey, bkBound, bkCnt, node_ids, nd, dinvA);
    k_x1b<<<NBK, 256, 0, stream>>>(partsKey, bkBound, bkCnt, nd, t1, b1, z, poolY);
    k_conv2g<<<GMAX * 32, 256, 0, stream>>>(partsKey, bkCnt, gBound,
                                            dinvA, z, poolY);
    k_out<<<GMAX, 128, 0, stream>>>(poolY, gBound, W2, b2, out);
}